// Round 17
// baseline (6794.527 us; speedup 1.0000x reference)
//
#include <hip/hip_runtime.h>
#include <hip/hip_bf16.h>
#include <stdint.h>

// Problem constants
#define Bsz 512
#define Tsz 512
#define Fsz 16
#define Hsz 256
#define HORZ 24

// 3 layers x 4 gate-slices x 8 batch-tiles = 96 blocks (halved h-traffic + web)
#define NG 4
#define NBT 8
#define BT 64
#define USL 64          // hidden units per slice (256 gate cols)
#define PD 8            // h slot depth (power of 2)
#define HBUF_ELEMS ((size_t)3*PD*Bsz*Hsz)
#define NFLAGS (3*NG*NBT)
#define AROW_B 512                  // bytes per staged h row (256 bf16)
#define ABUF_B (BT*AROW_B)          // 32 KiB
#define HTILE_B (BT*128)            // 8 KiB (64 rows x 64 units bf16)
#define CST_B (BT*USL*4)            // 16 KiB f32 cell state
#define SMEM_B (3*ABUF_B + HTILE_B + CST_B)   // 120 KiB -> 1 block/CU

#define POISON   0x7FC07FC0u                 // bf16 NaN pair: impossible for real h
#define POISON64 0x7FC07FC07FC07FC0ull

typedef float  f32x4  __attribute__((ext_vector_type(4)));
typedef float  f32x16 __attribute__((ext_vector_type(16)));
typedef __bf16 bf16x8 __attribute__((ext_vector_type(8)));
typedef uint32_t u32x2 __attribute__((ext_vector_type(2)));
typedef uint32_t u32x4 __attribute__((ext_vector_type(4)));

__device__ __forceinline__ float sigm(float v){ return 1.f/(1.f+__expf(-v)); }

// ---- verified sc01 (IC-coherent) helpers; only vmcnt(0) drains anywhere ----
__device__ __forceinline__ bf16x8 ld_sc01_b128(const void* p){
  bf16x8 r;
  asm volatile("global_load_dwordx4 %0, %1, off sc0 sc1" : "=&v"(r) : "v"(p) : "memory");
  return r;
}
__device__ __forceinline__ u32x2 ld_b64_async(const void* p){    // plain cached (x)
  u32x2 r;
  asm volatile("global_load_dwordx2 %0, %1, off" : "=&v"(r) : "v"(p) : "memory");
  return r;
}
__device__ __forceinline__ void st_sc01_b128(void* p, u32x4 v){
  asm volatile("global_store_dwordx4 %0, %1, off sc0 sc1" :: "v"(p), "v"(v) : "memory");
}
__device__ __forceinline__ void st_sc01_b32(void* p, uint32_t v){
  asm volatile("global_store_dword %0, %1, off sc0 sc1" :: "v"(p), "v"(v) : "memory");
}
__device__ __forceinline__ uint32_t ld_sc01_b32(const void* p){
  uint32_t r;
  asm volatile("global_load_dword %0, %1, off sc0 sc1\n\ts_waitcnt vmcnt(0)"
    : "=&v"(r) : "v"(p) : "memory");
  return r;
}
__device__ __forceinline__ void wait_flag(const unsigned int* fp, int target){
  int guard = 0;
  while ((int)ld_sc01_b32(fp) < target){
    __builtin_amdgcn_s_sleep(1);
    if (++guard > (1<<18)) break;   // fail-fast: wrong result, never a timeout
  }
}
__device__ __forceinline__ bool poison_free(const bf16x8* v){
  bool ok = true;
  #pragma unroll
  for (int j=0;j<4;++j){
    u32x4 uv = __builtin_bit_cast(u32x4, v[j]);
    ok = ok && (uv[0] != POISON) && (uv[2] != POISON);   // one check per 8B granule
  }
  return ok;
}
__device__ __forceinline__ void poll_load4(bf16x8* dst, const __bf16* src){
  int guard = 0;
  for(;;){
    #pragma unroll
    for (int j=0;j<4;++j) dst[j] = ld_sc01_b128(src + j*8);
    asm volatile("s_waitcnt vmcnt(0)" ::: "memory");
    __builtin_amdgcn_sched_barrier(0);
    if (poison_free(dst)) break;
    __builtin_amdgcn_s_sleep(1);
    if (++guard > (1<<16)) break;   // fail-fast
  }
}

template<bool L0>
__device__ __forceinline__ void lstm_body(
    int l, int g, int nb, int tid,
    const float* __restrict__ xin,
    const float* __restrict__ Wih0,
    const float* __restrict__ Wih12,
    const float* __restrict__ Whh,
    const float* __restrict__ bih,
    const float* __restrict__ bhh,
    __bf16* __restrict__ hb,
    unsigned int* __restrict__ flags,
    char* smem)
{
  char* ain0  = smem;                 // hin buffer parity 0 (L0: 32B-row x buffer)
  char* ain1  = smem + ABUF_B;        // parity 1
  char* hrc   = smem + 2*ABUF_B;      // hrec buffer (single)
  char* htile = smem + 3*ABUF_B;      // h-out tile [64][128B]
  float* cstp = (float*)(smem + 3*ABUF_B + HTILE_B);   // [64 rows][64 units] f32

  const int lane = tid & 63;
  const int wid  = tid >> 6;          // 8 waves = 8 N-slices of 32 cols
  const int b0   = nb * BT;

  const int colL = wid*32 + (lane & 31);        // this lane's gate-col (0..255)
  const int hi   = lane >> 5;
  const int kg8  = hi * 8;
  const int kg16 = hi * 16;
  const int gate = colL & 3;
  const int unitL = colL >> 2;                  // 0..63
  const int R    = gate*Hsz + g*USL + unitL;    // weight row
  const float bias = bih[l*4*Hsz + R] + bhh[l*4*Hsz + R];
  const int rowA = lane & 31;                   // M-tile0 row; tile1 = +32
  const int swzA = (rowA & 7) << 4;             // same key for both tiles
  const bool q2 = (gate == 2);

  // ---- one-time: W slice -> registers (r6-verbatim loader) ----
  constexpr int NC = L0 ? 17 : 32;              // K chunks of 16
  bf16x8 w[NC];
  {
    const float* recB = Whh + ((size_t)l*4*Hsz + R)*Hsz;
    #pragma unroll
    for (int c=0;c<NC;++c){
      const float* p;
      if constexpr (L0) p = (c==0) ? (Wih0 + (size_t)R*Fsz + kg8)
                                   : (recB + (c-1)*16 + kg8);
      else              p = (c<16) ? (Wih12 + ((size_t)(l-1)*4*Hsz + R)*Hsz + c*16 + kg8)
                                   : (recB + (c-16)*16 + kg8);
      f32x4 u0 = *(const f32x4*)p;
      f32x4 u1 = *(const f32x4*)(p+4);
      bf16x8 t;
      #pragma unroll
      for (int j=0;j<4;++j){ t[j]=(__bf16)u0[j]; t[j+4]=(__bf16)u1[j]; }
      w[c] = t;
    }
  }

  // staging roles: 8 threads per 512B row
  const int srow = tid >> 3, sq = tid & 7;
  const int sswz = (srow & 7) << 4;
  const size_t sgrow = (size_t)(b0 + srow) * Hsz;

  unsigned int* myflag = flags + ((l*NG+g)*NBT + nb);
  auto slotp = [&](int ll, int s){ return hb + ((size_t)ll*PD + (s&(PD-1)))*Bsz*Hsz; };

  // ---- prologue: zero hrc (h(-1)=0) + zero cst; stage input(0) into ain0 ----
  {
    u32x4 z = {0,0,0,0};
    #pragma unroll
    for (int j=0;j<4;++j) *(u32x4*)(hrc + tid*64 + j*16) = z;     // 32K
    *(u32x4*)((char*)cstp + tid*32)      = z;                      // 16K
    *(u32x4*)((char*)cstp + tid*32 + 16) = z;
  }
  if constexpr (L0){
    u32x2 xv = ld_b64_async(xin + ((size_t)(b0+srow)*Tsz + 0)*Fsz + sq*2);
    asm volatile("s_waitcnt vmcnt(0)" ::: "memory");
    __builtin_amdgcn_sched_barrier(0);
    char* d = ain0 + srow*32 + sq*4;
    *(__bf16*)(d)   = (__bf16)__uint_as_float(xv[0]);
    *(__bf16*)(d+2) = (__bf16)__uint_as_float(xv[1]);
  } else {
    bf16x8 av[4];
    poll_load4(av, slotp(l-1,0) + sgrow + sq*32);
    #pragma unroll
    for (int j=0;j<4;++j)
      *(bf16x8*)(ain0 + srow*AROW_B + ((sq*64 + j*16) ^ sswz)) = av[j];
  }
  __syncthreads();

  for (int t=0; t<Tsz; ++t){
    // ---- A: lazy WAR guard (every 4 steps, off critical path) ----
    if (l < 2 && (t & 3) == 0 && t >= 4 && tid < NG)
      wait_flag(flags + (((l+1)*NG + tid)*NBT + nb), t-3);

    char* aprd = (t&1) ? ain1 : ain0;   // hin read buffer (staged last step)
    char* apwr = (t&1) ? ain0 : ain1;   // hin prefetch target
    bf16x8 hiv[4]; const __bf16* pfsrc = nullptr;
    const bool pfon = (!L0) && (t+1 < Tsz);

    // ---- B: hrec DATA-POLL (blocking), then issue hin(t+1) prefetch ----
    if constexpr (L0){
      u32x2 xv = ld_b64_async(xin + ((size_t)(b0+srow)*Tsz + t)*Fsz + sq*2);
      bf16x8 hrv[4];
      if (t > 0) poll_load4(hrv, slotp(l,t-1) + sgrow + sq*32);
      else { asm volatile("s_waitcnt vmcnt(0)" ::: "memory");
             __builtin_amdgcn_sched_barrier(0); }
      char* d = ain0 + srow*32 + sq*4;
      *(__bf16*)(d)   = (__bf16)__uint_as_float(xv[0]);
      *(__bf16*)(d+2) = (__bf16)__uint_as_float(xv[1]);
      if (t > 0){
        #pragma unroll
        for (int j=0;j<4;++j)
          *(bf16x8*)(hrc + srow*AROW_B + ((sq*64 + j*16) ^ sswz)) = hrv[j];
      }
    } else {
      if (t > 0){
        bf16x8 hrv[4];
        poll_load4(hrv, slotp(l,t-1) + sgrow + sq*32);
        #pragma unroll
        for (int j=0;j<4;++j)
          *(bf16x8*)(hrc + srow*AROW_B + ((sq*64 + j*16) ^ sswz)) = hrv[j];
      }
      if (pfon){   // issue async; flies under MFMA, drained+checked in F
        pfsrc = slotp(l-1,t+1) + sgrow + sq*32;
        #pragma unroll
        for (int j=0;j<4;++j) hiv[j] = ld_sc01_b128(pfsrc + j*8);
      }
    }
    __syncthreads();

    // ---- C: MFMA, both M-tiles (rows 0-31 / 32-63), W shared ----
    f32x16 acc0, acc1;
    #pragma unroll
    for (int i=0;i<16;++i){ acc0[i]=0.f; acc1[i]=0.f; }
    #pragma unroll
    for (int c=0;c<NC;++c){
      bf16x8 a0, a1;
      if constexpr (L0){
        if (c==0){ a0 = *(const bf16x8*)(ain0 + rowA*32 + kg16);
                   a1 = *(const bf16x8*)(ain0 + (rowA+32)*32 + kg16); }
        else { int off = (((c-1)*32) + kg16) ^ swzA;
               a0 = *(const bf16x8*)(hrc + rowA*AROW_B + off);
               a1 = *(const bf16x8*)(hrc + (rowA+32)*AROW_B + off); }
      } else {
        const char* bse = (c<16) ? aprd : hrc;
        int cc = (c<16) ? c : c-16;
        int off = ((cc*32) + kg16) ^ swzA;
        a0 = *(const bf16x8*)(bse + rowA*AROW_B + off);
        a1 = *(const bf16x8*)(bse + (rowA+32)*AROW_B + off);
      }
      acc0 = __builtin_amdgcn_mfma_f32_32x32x16_bf16(a0, w[c], acc0, 0,0,0);
      acc1 = __builtin_amdgcn_mfma_f32_32x32x16_bf16(a1, w[c], acc1, 0,0,0);
    }

    // ---- D: epilogue, both tiles; f32 cell state in LDS ----
    #pragma unroll
    for (int mt=0; mt<2; ++mt){
      #pragma unroll
      for (int i=0;i<16;++i){
        float v  = (mt ? acc1[i] : acc0[i]) + bias;
        float vv = q2 ? 2.f*v : v;
        float sg = sigm(vv);
        float act = q2 ? (2.f*sg - 1.f) : sg;   // tanh for g-gate, sigmoid else
        float a1 = __shfl_xor(act,1,64);        // f
        float a2 = __shfl_xor(act,2,64);        // g
        float a3 = __shfl_xor(act,3,64);        // o
        if (gate==0){
          int r = (i&3) + 8*(i>>2) + 4*hi;      // 32x32 C/D row map
          int idx = (mt*32 + r)*64 + unitL;
          float cn = a1*cstp[idx] + act*a2;
          cstp[idx] = cn;
          float th = 2.f*sigm(2.f*cn) - 1.f;    // tanh(cn)
          float hv = a3*th;
          *(__bf16*)(htile + (mt*32 + r)*128 + unitL*2) = (__bf16)hv;
        }
      }
    }
    __syncthreads();

    // ---- F: h store + forward poison; drain; check+land hin; publish ----
    {
      int row = tid>>3, q = tid&7;
      u32x4 v = *(const u32x4*)(htile + row*128 + q*16);
      u32x4 pz = {POISON,POISON,POISON,POISON};
      st_sc01_b128(slotp(l,t)   + (size_t)(b0+row)*Hsz + g*USL + q*8, v);
      st_sc01_b128(slotp(l,t+2) + (size_t)(b0+row)*Hsz + g*USL + q*8, pz);
    }
    asm volatile("s_waitcnt vmcnt(0)" ::: "memory");   // drains stores + prefetch
    __builtin_amdgcn_sched_barrier(0);
    if (pfon){
      if (!poison_free(hiv)) poll_load4(hiv, pfsrc);   // rare: l-1 not there yet
      #pragma unroll
      for (int j=0;j<4;++j)
        *(bf16x8*)(apwr + srow*AROW_B + ((sq*64 + j*16) ^ sswz)) = hiv[j];
    }
    __syncthreads();
    if (tid==0) st_sc01_b32(myflag, (uint32_t)(t+1));  // progress marker (WAR only)
  }
}

__global__ __launch_bounds__(512, 2) void lstm_persist(
    const float* __restrict__ xin,
    const float* __restrict__ Wih0,
    const float* __restrict__ Wih12,
    const float* __restrict__ Whh,
    const float* __restrict__ bih,
    const float* __restrict__ bhh,
    __bf16* __restrict__ hb,
    unsigned int* __restrict__ flags)
{
  __shared__ __align__(16) char smem[SMEM_B];   // 120 KiB -> 1 block/CU
  const int bid = blockIdx.x;
  const int l   = bid >> 5;          // 0..2
  const int g   = (bid >> 3) & 3;    // gate-slice 0..3
  const int nb  = bid & 7;           // batch tile
  const int tid = threadIdx.x;
  if (l == 0)
    lstm_body<true >(l,g,nb,tid, xin,Wih0,Wih12,Whh,bih,bhh, hb,flags, smem);
  else
    lstm_body<false>(l,g,nb,tid, xin,Wih0,Wih12,Whh,bih,bhh, hb,flags, smem);
}

// Pre-fill all h slots with NaN poison + zero flags (replay-safe init)
__global__ void init_ws(uint32_t* __restrict__ hb32, uint32_t* __restrict__ flags)
{
  size_t i = (size_t)blockIdx.x*blockDim.x + threadIdx.x;
  size_t n = (HBUF_ELEMS*2)/16;
  if (i < n){
    u32x4 v = {POISON, POISON, POISON, POISON};
    *(u32x4*)(hb32 + i*4) = v;
  }
  if (i < NFLAGS) flags[i] = 0;
}

__global__ void fc_kernel(const __bf16* __restrict__ hb,
                          const float* __restrict__ fcW,
                          const float* __restrict__ fcb,
                          float* __restrict__ out)
{
  __shared__ float hs[Hsz];
  int b = blockIdx.x;
  const __bf16* hp = hb + ((size_t)(2*PD + ((Tsz-1)&(PD-1))))*Bsz*Hsz + (size_t)b*Hsz;
  for (int i = threadIdx.x; i < Hsz; i += 64) hs[i] = (float)hp[i];
  __syncthreads();
  int o = threadIdx.x;
  if (o < HORZ) {
    float a = fcb[o];
    #pragma unroll 8
    for (int u=0; u<Hsz; ++u) a += hs[u]*fcW[o*Hsz + u];
    out[b*HORZ + o] = a;
  }
}

extern "C" void kernel_launch(void* const* d_in, const int* in_sizes, int n_in,
                              void* d_out, int out_size, void* d_ws, size_t ws_size,
                              hipStream_t stream)
{
  const float* x     = (const float*)d_in[0];
  const float* Wih0  = (const float*)d_in[1];
  const float* Wih12 = (const float*)d_in[2];
  const float* Whh   = (const float*)d_in[3];
  const float* bih   = (const float*)d_in[4];
  const float* bhh   = (const float*)d_in[5];
  const float* fcW   = (const float*)d_in[6];
  const float* fcb   = (const float*)d_in[7];

  __bf16* hb = (__bf16*)d_ws;
  unsigned int* flags = (unsigned int*)((char*)d_ws + HBUF_ELEMS*2);

  // poison h slots + zero flags (kernel, since memset can't write 0x7FC07FC0)
  size_t nchunk = (HBUF_ELEMS*2)/16;
  int ib = (int)((nchunk + 255) / 256);
  hipLaunchKernelGGL(init_ws, dim3(ib), dim3(256), 0, stream, (uint32_t*)hb, flags);

  hipLaunchKernelGGL(lstm_persist, dim3(3*NG*NBT), dim3(512), 0, stream,
                     x, Wih0, Wih12, Whh, bih, bhh, hb, flags);
  hipLaunchKernelGGL(fc_kernel, dim3(Bsz), dim3(64), 0, stream, hb, fcW, fcb, (float*)d_out);
}

// Round 18
// 3202.380 us; speedup vs baseline: 2.1217x; 2.1217x over previous
//
#include <hip/hip_runtime.h>
#include <hip/hip_bf16.h>
#include <stdint.h>

// Problem constants
#define Bsz 512
#define Tsz 512
#define Fsz 16
#define Hsz 256
#define HORZ 24

// 3 layers x 8 gate-slices x 8 batch-tiles = 192 blocks (round-6/10 geometry)
#define NG 8
#define NBT 8
#define BT 64
#define USL 32          // hidden units per slice (128 gate cols)
#define PD 8            // h slot depth (power of 2)
#define HBUF_ELEMS ((size_t)3*PD*Bsz*Hsz)
#define NFLAGS (3*NG*NBT)
#define AROW_B 512                  // bytes per staged h row (256 bf16)
#define ABUF_B (BT*AROW_B)          // 32 KiB per ain buffer
#define HTILE_B (BT*64)             // 4 KiB
#define SMEM_B (3*ABUF_B + HTILE_B) // 100 KiB -> 1 block/CU

#define POISON   0x7FC07FC0u                 // bf16 NaN pair: impossible for real h
#define POISON64 0x7FC07FC07FC07FC0ull

typedef float  f32x4  __attribute__((ext_vector_type(4)));
typedef float  f32x16 __attribute__((ext_vector_type(16)));
typedef __bf16 bf16x8 __attribute__((ext_vector_type(8)));
typedef uint32_t u32x2 __attribute__((ext_vector_type(2)));
typedef uint32_t u32x4 __attribute__((ext_vector_type(4)));

__device__ __forceinline__ float sigm(float v){ return 1.f/(1.f+__expf(-v)); }

// ---- verified sc01 (IC-coherent) helpers; only vmcnt(0) drains anywhere ----
__device__ __forceinline__ bf16x8 ld_sc01_b128(const void* p){   // async
  bf16x8 r;
  asm volatile("global_load_dwordx4 %0, %1, off sc0 sc1" : "=&v"(r) : "v"(p) : "memory");
  return r;
}
__device__ __forceinline__ u32x2 ld_b64_async(const void* p){    // plain cached (x)
  u32x2 r;
  asm volatile("global_load_dwordx2 %0, %1, off" : "=&v"(r) : "v"(p) : "memory");
  return r;
}
__device__ __forceinline__ void st_sc01_b64(void* p, uint64_t v){
  asm volatile("global_store_dwordx2 %0, %1, off sc0 sc1" :: "v"(p), "v"(v) : "memory");
}
__device__ __forceinline__ void st_sc01_b32(void* p, uint32_t v){
  asm volatile("global_store_dword %0, %1, off sc0 sc1" :: "v"(p), "v"(v) : "memory");
}
__device__ __forceinline__ uint32_t ld_sc01_b32(const void* p){  // sync (self-draining)
  uint32_t r;
  asm volatile("global_load_dword %0, %1, off sc0 sc1\n\ts_waitcnt vmcnt(0)"
    : "=&v"(r) : "v"(p) : "memory");
  return r;
}
__device__ __forceinline__ void wait_flag(const unsigned int* fp, int target){
  int guard = 0;
  while ((int)ld_sc01_b32(fp) < target){
    __builtin_amdgcn_s_sleep(1);
    if (++guard > (1<<18)) break;   // fail-fast: wrong result, never a timeout
  }
}
__device__ __forceinline__ bool poison_free(const bf16x8* v){
  bool ok = true;
  #pragma unroll
  for (int j=0;j<4;++j){
    u32x4 uv = __builtin_bit_cast(u32x4, v[j]);
    ok = ok && (uv[0] != POISON) && (uv[2] != POISON);   // one check per 8B granule
  }
  return ok;
}
// poll-load 64B until non-poison (steady state: single RT, no retry)
__device__ __forceinline__ void poll_load4(bf16x8* dst, const __bf16* src){
  int guard = 0;
  for(;;){
    #pragma unroll
    for (int j=0;j<4;++j) dst[j] = ld_sc01_b128(src + j*8);
    asm volatile("s_waitcnt vmcnt(0)" ::: "memory");
    __builtin_amdgcn_sched_barrier(0);
    if (poison_free(dst)) break;
    __builtin_amdgcn_s_sleep(1);
    if (++guard > (1<<16)) break;   // fail-fast
  }
}

template<bool L0>
__device__ __forceinline__ void lstm_body(
    int l, int g, int nb, int tid,
    const float* __restrict__ xin,
    const float* __restrict__ Wih0,
    const float* __restrict__ Wih12,
    const float* __restrict__ Whh,
    const float* __restrict__ bih,
    const float* __restrict__ bhh,
    __bf16* __restrict__ hb,
    unsigned int* __restrict__ flags,
    char* smem)
{
  char* ain0  = smem;                 // hin buffer parity 0 (L0: 32B-row x buffer)
  char* ain1  = smem + ABUF_B;        // parity 1
  char* hrc   = smem + 2*ABUF_B;      // hrec buffer (single)
  char* htile = smem + 3*ABUF_B;      // h-out coalescing tile [64][64B]

  const int lane = tid & 63;
  const int wid  = tid >> 6;          // 8 waves: 2M x 4N
  const int wm   = wid >> 2;
  const int wn   = wid & 3;
  const int b0   = nb * BT;
  const int m0   = wm * 32;
  const int n0   = wn * 32;

  const int colL = n0 + (lane & 31);            // this lane's gate-col (0..127)
  const int hi   = lane >> 5;
  const int kg8  = hi * 8;
  const int kg16 = hi * 16;
  const int R    = (colL&3)*Hsz + g*USL + (colL>>2);   // weight row
  const float bias = bih[l*4*Hsz + R] + bhh[l*4*Hsz + R];
  const int rowA = m0 + (lane & 31);            // batch row within tile
  const int swzA = (rowA & 7) << 4;

  // ---- one-time: W slice -> registers (round-6 verbatim) ----
  constexpr int NC = L0 ? 17 : 32;              // K chunks of 16
  bf16x8 w[NC];
  {
    const float* recB = Whh + ((size_t)l*4*Hsz + R)*Hsz;
    #pragma unroll
    for (int c=0;c<NC;++c){
      const float* p;
      if constexpr (L0) p = (c==0) ? (Wih0 + (size_t)R*Fsz + kg8)
                                   : (recB + (c-1)*16 + kg8);
      else              p = (c<16) ? (Wih12 + ((size_t)(l-1)*4*Hsz + R)*Hsz + c*16 + kg8)
                                   : (recB + (c-16)*16 + kg8);
      f32x4 u0 = *(const f32x4*)p;
      f32x4 u1 = *(const f32x4*)(p+4);
      bf16x8 t;
      #pragma unroll
      for (int j=0;j<4;++j){ t[j]=(__bf16)u0[j]; t[j+4]=(__bf16)u1[j]; }
      w[c] = t;
    }
  }

  // staging roles: 8 threads per 512B row
  const int srow = tid >> 3, sq = tid & 7;
  const int sswz = (srow & 7) << 4;
  const size_t sgrow = (size_t)(b0 + srow) * Hsz;

  float cst[16];
  #pragma unroll
  for (int i=0;i<16;++i) cst[i]=0.f;

  unsigned int* myflag = flags + ((l*NG+g)*NBT + nb);
  const bool q2 = ((colL & 3) == 2);
  auto slotp = [&](int ll, int s){ return hb + ((size_t)ll*PD + (s&(PD-1)))*Bsz*Hsz; };

  // ---- prologue: zero hrec (h(-1)=0); stage input(0) into ain0 (data-poll) ----
  {
    u32x4 z = {0,0,0,0};
    #pragma unroll
    for (int j=0;j<4;++j) *(u32x4*)(hrc + tid*64 + j*16) = z;
  }
  if constexpr (L0){
    u32x2 xv = ld_b64_async(xin + ((size_t)(b0+srow)*Tsz + 0)*Fsz + sq*2);
    asm volatile("s_waitcnt vmcnt(0)" ::: "memory");
    __builtin_amdgcn_sched_barrier(0);
    char* d = ain0 + srow*32 + sq*4;
    *(__bf16*)(d)   = (__bf16)__uint_as_float(xv[0]);
    *(__bf16*)(d+2) = (__bf16)__uint_as_float(xv[1]);
  } else {
    bf16x8 av[4];
    poll_load4(av, slotp(l-1,0) + sgrow + sq*32);
    #pragma unroll
    for (int j=0;j<4;++j)
      *(bf16x8*)(ain0 + srow*AROW_B + ((sq*64 + j*16) ^ sswz)) = av[j];
  }
  __syncthreads();

  for (int t=0; t<Tsz; ++t){
    // ---- A: lazy WAR guard only (every 4 steps; off critical path) ----
    if (l < 2 && (t & 3) == 0){
      if (tid < 8 && t >= 4)
        wait_flag(flags + (((l+1)*NG + tid)*NBT + nb), t-3);
      __syncthreads();
    }

    char* aprd = (t&1) ? ain1 : ain0;   // l>=1 hin read buffer
    char* apwr = (t&1) ? ain0 : ain1;   // l>=1 hin prefetch target
    bf16x8 hiv[4];                       // hin(t+1) prefetch regs
    const __bf16* pfsrc = nullptr;
    const bool pfon = (!L0) && (t+1 < Tsz);

    // ---- B: hrec DATA-POLL (1 RT steady state); then issue hin prefetch ----
    if constexpr (L0){
      u32x2 xv = ld_b64_async(xin + ((size_t)(b0+srow)*Tsz + t)*Fsz + sq*2);
      bf16x8 hrv[4];
      if (t > 0) poll_load4(hrv, slotp(l,t-1) + sgrow + sq*32);
      else { asm volatile("s_waitcnt vmcnt(0)" ::: "memory");
             __builtin_amdgcn_sched_barrier(0); }
      char* d = ain0 + srow*32 + sq*4;
      *(__bf16*)(d)   = (__bf16)__uint_as_float(xv[0]);
      *(__bf16*)(d+2) = (__bf16)__uint_as_float(xv[1]);
      if (t > 0){
        #pragma unroll
        for (int j=0;j<4;++j)
          *(bf16x8*)(hrc + srow*AROW_B + ((sq*64 + j*16) ^ sswz)) = hrv[j];
      }
      __syncthreads();
    } else {
      if (t > 0){
        bf16x8 hrv[4];
        poll_load4(hrv, slotp(l,t-1) + sgrow + sq*32);
        #pragma unroll
        for (int j=0;j<4;++j)
          *(bf16x8*)(hrc + srow*AROW_B + ((sq*64 + j*16) ^ sswz)) = hrv[j];
      }
      if (pfon){   // issue async; flies under MFMA, drained+checked in F
        pfsrc = slotp(l-1,t+1) + sgrow + sq*32;
        #pragma unroll
        for (int j=0;j<4;++j) hiv[j] = ld_sc01_b128(pfsrc + j*8);
      }
      __syncthreads();
    }

    // ---- C: MFMA (round-6 verbatim, split A sources) ----
    f32x16 acc;
    #pragma unroll
    for (int i=0;i<16;++i) acc[i]=0.f;
    #pragma unroll
    for (int c=0;c<NC;++c){
      bf16x8 af;
      if constexpr (L0){
        if (c==0) af = *(const bf16x8*)(ain0 + rowA*32 + kg16);
        else      af = *(const bf16x8*)(hrc + rowA*AROW_B + ((((c-1)*32) + kg16) ^ swzA));
      } else {
        if (c<16) af = *(const bf16x8*)(aprd + rowA*AROW_B + (((c*32) + kg16) ^ swzA));
        else      af = *(const bf16x8*)(hrc  + rowA*AROW_B + ((((c-16)*32) + kg16) ^ swzA));
      }
      acc = __builtin_amdgcn_mfma_f32_32x32x16_bf16(af, w[c], acc, 0,0,0);
    }

    // ---- D: epilogue (round-6 verbatim) ----
    #pragma unroll
    for (int i=0;i<16;++i){
      float v  = acc[i] + bias;
      float vv = q2 ? 2.f*v : v;
      float sg = sigm(vv);
      float act = q2 ? (2.f*sg - 1.f) : sg;   // tanh for g-gate, sigmoid otherwise
      float a1 = __shfl_xor(act,1,64);        // f
      float a2 = __shfl_xor(act,2,64);        // g
      float a3 = __shfl_xor(act,3,64);        // o
      if ((lane&3)==0){
        float cn = a1*cst[i] + act*a2;
        cst[i] = cn;
        float th = 2.f*sigm(2.f*cn) - 1.f;    // tanh(cn)
        float hv = a3*th;
        int r = (i&3) + 8*(i>>2) + 4*hi;      // 32x32 C/D row map
        int unit = colL >> 2;
        *(__bf16*)(htile + (m0 + r)*64 + unit*2) = (__bf16)hv;
      }
    }
    __syncthreads();

    // ---- F: h store + forward poison; drain; check+land hin; publish ----
    {
      uint64_t v = *(const uint64_t*)(htile + srow*64 + sq*8);
      st_sc01_b64(slotp(l,t)   + sgrow + g*USL + sq*4, v);
      st_sc01_b64(slotp(l,t+2) + sgrow + g*USL + sq*4, POISON64);  // pre-poison slot t+2
    }
    asm volatile("s_waitcnt vmcnt(0)" ::: "memory");   // drains stores + prefetch loads
    __builtin_amdgcn_sched_barrier(0);
    if (pfon){
      if (!poison_free(hiv)) poll_load4(hiv, pfsrc);   // rare: l-1 not there yet
      #pragma unroll
      for (int j=0;j<4;++j)
        *(bf16x8*)(apwr + srow*AROW_B + ((sq*64 + j*16) ^ sswz)) = hiv[j];
    }
    __syncthreads();
    if (tid==0) st_sc01_b32(myflag, (uint32_t)(t+1));  // progress marker (WAR only)
  }
}

__global__ __launch_bounds__(512, 2) void lstm_persist(
    const float* __restrict__ xin,
    const float* __restrict__ Wih0,
    const float* __restrict__ Wih12,
    const float* __restrict__ Whh,
    const float* __restrict__ bih,
    const float* __restrict__ bhh,
    __bf16* __restrict__ hb,
    unsigned int* __restrict__ flags)
{
  __shared__ __align__(16) char smem[SMEM_B];   // 100 KiB -> 1 block/CU
  const int bid = blockIdx.x;
  const int l   = bid >> 6;          // 0..2
  const int g   = (bid >> 3) & 7;    // gate-slice
  const int nb  = bid & 7;           // batch tile
  const int tid = threadIdx.x;
  if (l == 0)
    lstm_body<true >(l,g,nb,tid, xin,Wih0,Wih12,Whh,bih,bhh, hb,flags, smem);
  else
    lstm_body<false>(l,g,nb,tid, xin,Wih0,Wih12,Whh,bih,bhh, hb,flags, smem);
}

// Pre-fill all h slots with NaN poison + zero flags (replay-safe init)
__global__ void init_ws(uint32_t* __restrict__ hb32, uint32_t* __restrict__ flags)
{
  size_t i = (size_t)blockIdx.x*blockDim.x + threadIdx.x;
  size_t n = (HBUF_ELEMS*2)/16;   // #u32x4 chunks
  if (i < n){
    u32x4 v = {POISON, POISON, POISON, POISON};
    *(u32x4*)(hb32 + i*4) = v;
  }
  if (i < NFLAGS) flags[i] = 0;
}

__global__ void fc_kernel(const __bf16* __restrict__ hb,
                          const float* __restrict__ fcW,
                          const float* __restrict__ fcb,
                          float* __restrict__ out)
{
  __shared__ float hs[Hsz];
  int b = blockIdx.x;
  const __bf16* hp = hb + ((size_t)(2*PD + ((Tsz-1)&(PD-1))))*Bsz*Hsz + (size_t)b*Hsz;
  for (int i = threadIdx.x; i < Hsz; i += 64) hs[i] = (float)hp[i];
  __syncthreads();
  int o = threadIdx.x;
  if (o < HORZ) {
    float a = fcb[o];
    #pragma unroll 8
    for (int u=0; u<Hsz; ++u) a += hs[u]*fcW[o*Hsz + u];
    out[b*HORZ + o] = a;
  }
}

extern "C" void kernel_launch(void* const* d_in, const int* in_sizes, int n_in,
                              void* d_out, int out_size, void* d_ws, size_t ws_size,
                              hipStream_t stream)
{
  const float* x     = (const float*)d_in[0];
  const float* Wih0  = (const float*)d_in[1];
  const float* Wih12 = (const float*)d_in[2];
  const float* Whh   = (const float*)d_in[3];
  const float* bih   = (const float*)d_in[4];
  const float* bhh   = (const float*)d_in[5];
  const float* fcW   = (const float*)d_in[6];
  const float* fcb   = (const float*)d_in[7];

  __bf16* hb = (__bf16*)d_ws;
  unsigned int* flags = (unsigned int*)((char*)d_ws + HBUF_ELEMS*2);

  // poison h slots + zero flags (kernel, since memset can't write 0x7FC07FC0)
  size_t nchunk = (HBUF_ELEMS*2)/16;
  int ib = (int)((nchunk + 255) / 256);
  hipLaunchKernelGGL(init_ws, dim3(ib), dim3(256), 0, stream, (uint32_t*)hb, flags);

  hipLaunchKernelGGL(lstm_persist, dim3(3*NG*NBT), dim3(512), 0, stream,
                     x, Wih0, Wih12, Whh, bih, bhh, hb, flags);
  hipLaunchKernelGGL(fc_kernel, dim3(Bsz), dim3(64), 0, stream, hb, fcW, fcb, (float*)d_out);
}